// Round 9
// baseline (17259.543 us; speedup 1.0000x reference)
//
#include <hip/hip_runtime.h>
#include <math.h>

#define B 512
#define S_IN 128
#define S_OUT 64
#define T_DEC 63

// ---- workspace layout (floats); fits the proven ws floor of 140.5 MB ----
#define O_H0   0
#define O_H1   524288
#define O_C    1048576
#define O_BAR  1572864                  // 4 floats reserved (barrier counter)
#define O_HS0  1572868                  // hs0: 128*512*512 = 33,554,432
#define O_P1   (O_HS0 + 33554432)      // 35,127,300 floats = 140.509 MB
// decoder-phase aliases inside the (dead-after-encoder) hs0 region:
#define D_HT0  O_HS0
#define D_HT1  (O_HS0 + 524288)
#define D_CT0  (O_HS0 + 1048576)
#define D_CT1  (O_HS0 + 1572864)
#define D_PWT  (O_HS0 + 2097152)       // pwt: 1024*128

// ===========================================================================
// Encoder step (256 thr, 64x64 tile, 4x4 micro) — round-2 validated, verbatim.
// ===========================================================================
template<int MODE>
__global__ __launch_bounds__(256)
void enc_step(const float* __restrict__ Wih, const float* __restrict__ Whh,
              const float* __restrict__ bias, const int* __restrict__ tok,
              const float* __restrict__ emb, const float* __restrict__ seqin,
              const float* __restrict__ h_in, float* __restrict__ h_out,
              float* __restrict__ c_st, float* __restrict__ seqout,
              const float* __restrict__ p1, int t)
{
    constexpr int KE = (MODE==0) ? 64 : (MODE==2 ? 512 : 0);
    constexpr int K  = KE + 256;
    constexpr int NK = K/16;

    const int dir   = blockIdx.z;
    const int t_eff = dir ? (S_IN-1-t) : t;
    const int hseg  = (MODE==0) ? dir*256 : 512 + dir*256;

    const float* Wih_d = Wih + (size_t)dir*1024*KE;
    const float* Whh_d = Whh + (size_t)dir*1024*256;
    const float* b_d   = bias + dir*1024;

    __shared__ float As[16][64];
    __shared__ float Bs[16][64];

    const int tid = threadIdx.x;
    const int bm0 = blockIdx.x*64;
    const int bn0 = blockIdx.y*64;

    const int la_m  = tid >> 2;
    const int la_k  = (tid & 3) << 2;
    const int a_row = bm0 + la_m;

    const int lb_n = tid >> 2;
    const int lb_k = (tid & 3) << 2;
    const int n_g  = bn0 + lb_n;
    const int b_j  = (n_g & 3)*256 + (n_g >> 2);

    int tokidx = 0;
    if (MODE==0) tokidx = tok[t_eff*B + a_row];

    const int tm = (tid >> 4) << 2;
    const int tn = (tid & 15) << 2;

    float acc[4][4] = {};

    auto loadA = [&](int kt) -> float4 {
        int k = kt*16 + la_k;
        if (MODE==0) {
            if (k < 64) return *(const float4*)&emb[(size_t)tokidx*64 + k];
            return *(const float4*)&h_in[(size_t)a_row*1024 + hseg + (k-64)];
        } else if (MODE==2) {
            if (k < 512) return *(const float4*)&seqin[((size_t)t_eff*B + a_row)*512 + k];
            return *(const float4*)&h_in[(size_t)a_row*1024 + hseg + (k-512)];
        } else {
            return *(const float4*)&h_in[(size_t)a_row*1024 + hseg + k];
        }
    };
    auto loadB = [&](int kt) -> float4 {
        int k = kt*16 + lb_k;
        if (KE && k < KE) return *(const float4*)&Wih_d[(size_t)b_j*KE + k];
        return *(const float4*)&Whh_d[(size_t)b_j*256 + (k-KE)];
    };

    float4 aR = loadA(0), bR = loadB(0);
    for (int kt=0; kt<NK; ++kt) {
        __syncthreads();
        As[la_k+0][la_m]=aR.x; As[la_k+1][la_m]=aR.y; As[la_k+2][la_m]=aR.z; As[la_k+3][la_m]=aR.w;
        Bs[lb_k+0][lb_n]=bR.x; Bs[lb_k+1][lb_n]=bR.y; Bs[lb_k+2][lb_n]=bR.z; Bs[lb_k+3][lb_n]=bR.w;
        __syncthreads();
        if (kt+1 < NK) { aR = loadA(kt+1); bR = loadB(kt+1); }
        #pragma unroll
        for (int k=0;k<16;k++){
            const float4 a = *(const float4*)&As[k][tm];
            const float4 b = *(const float4*)&Bs[k][tn];
            acc[0][0]+=a.x*b.x; acc[0][1]+=a.x*b.y; acc[0][2]+=a.x*b.z; acc[0][3]+=a.x*b.w;
            acc[1][0]+=a.y*b.x; acc[1][1]+=a.y*b.y; acc[1][2]+=a.y*b.z; acc[1][3]+=a.y*b.w;
            acc[2][0]+=a.z*b.x; acc[2][1]+=a.z*b.y; acc[2][2]+=a.z*b.z; acc[2][3]+=a.z*b.w;
            acc[3][0]+=a.w*b.x; acc[3][1]+=a.w*b.y; acc[3][2]+=a.w*b.z; acc[3][3]+=a.w*b.w;
        }
    }

    const int jh = (bn0 + tn) >> 2;
    const float bi = b_d[0*256 + jh];
    const float bf = b_d[1*256 + jh];
    const float bg = b_d[2*256 + jh];
    const float bo = b_d[3*256 + jh];
    #pragma unroll
    for (int i=0;i<4;i++){
        const int brow = bm0 + tm + i;
        float xi = acc[i][0] + bi;
        float xf = acc[i][1] + bf;
        float xg = acc[i][2] + bg;
        float xo = acc[i][3] + bo;
        if (MODE==1) {
            const float4 pv = *(const float4*)&p1[((size_t)dir*512 + brow)*1024 + bn0 + tn];
            xi += pv.x; xf += pv.y; xg += pv.z; xo += pv.w;
        }
        float ig = 1.f/(1.f+expf(-xi));
        float fg = 1.f/(1.f+expf(-xf));
        float gg = tanhf(xg);
        float og = 1.f/(1.f+expf(-xo));
        size_t ci = (size_t)brow*1024 + hseg + jh;
        float cn = fg*c_st[ci] + ig*gg;
        float hn = og*tanhf(cn);
        c_st[ci]  = cn;
        h_out[ci] = hn;
        if (MODE==0) seqout[((size_t)t_eff*B + brow)*512 + dir*256 + jh] = hn;
    }
}

// ===========================================================================
// P1 precompute GEMM (round-2 validated, verbatim).
// ===========================================================================
__global__ __launch_bounds__(128)
void gemm_p1(const float* __restrict__ Wih, const float* __restrict__ hs0,
             float* __restrict__ p1out, int s0)
{
    constexpr int NK = 512/16;
    const int dir = blockIdx.z;

    __shared__ float As[16][64];
    __shared__ float Bs[16][64];

    const int tid = threadIdx.x;
    const int bm0 = blockIdx.x*64;
    const int bn0 = blockIdx.y*64;

    const int la_m  = tid >> 1;
    const int la_k  = (tid & 1) << 3;
    const int a_row = bm0 + la_m;

    const int srel  = blockIdx.x >> 3;
    const int sabs  = s0 + srel;
    const int t_eff = dir ? (S_IN-1-sabs) : sabs;
    const int a_b   = a_row & 511;

    const int n_g = bn0 + la_m;
    const int b_j = (n_g & 3)*256 + (n_g >> 2);

    const float* Wih_d = Wih + (size_t)dir*1024*512;

    const int tm = (tid >> 3) << 2;
    const int tn = (tid & 7) << 3;

    float acc[4][8] = {};

    auto loadA = [&](int kt, int q) -> float4 {
        int k = kt*16 + la_k + q*4;
        return *(const float4*)&hs0[((size_t)t_eff*B + a_b)*512 + k];
    };
    auto loadB = [&](int kt, int q) -> float4 {
        int k = kt*16 + la_k + q*4;
        return *(const float4*)&Wih_d[(size_t)b_j*512 + k];
    };

    float4 aR0 = loadA(0,0), aR1 = loadA(0,1);
    float4 bR0 = loadB(0,0), bR1 = loadB(0,1);
    for (int kt=0; kt<NK; ++kt) {
        __syncthreads();
        As[la_k+0][la_m]=aR0.x; As[la_k+1][la_m]=aR0.y; As[la_k+2][la_m]=aR0.z; As[la_k+3][la_m]=aR0.w;
        As[la_k+4][la_m]=aR1.x; As[la_k+5][la_m]=aR1.y; As[la_k+6][la_m]=aR1.z; As[la_k+7][la_m]=aR1.w;
        Bs[la_k+0][la_m]=bR0.x; Bs[la_k+1][la_m]=bR0.y; Bs[la_k+2][la_m]=bR0.z; Bs[la_k+3][la_m]=bR0.w;
        Bs[la_k+4][la_m]=bR1.x; Bs[la_k+5][la_m]=bR1.y; Bs[la_k+6][la_m]=bR1.z; Bs[la_k+7][la_m]=bR1.w;
        __syncthreads();
        if (kt+1 < NK) {
            aR0 = loadA(kt+1,0); aR1 = loadA(kt+1,1);
            bR0 = loadB(kt+1,0); bR1 = loadB(kt+1,1);
        }
        #pragma unroll
        for (int k=0;k<16;k++){
            const float4 a  = *(const float4*)&As[k][tm];
            const float4 b0 = *(const float4*)&Bs[k][tn];
            const float4 b1 = *(const float4*)&Bs[k][tn+4];
            acc[0][0]+=a.x*b0.x; acc[0][1]+=a.x*b0.y; acc[0][2]+=a.x*b0.z; acc[0][3]+=a.x*b0.w;
            acc[0][4]+=a.x*b1.x; acc[0][5]+=a.x*b1.y; acc[0][6]+=a.x*b1.z; acc[0][7]+=a.x*b1.w;
            acc[1][0]+=a.y*b0.x; acc[1][1]+=a.y*b0.y; acc[1][2]+=a.y*b0.z; acc[1][3]+=a.y*b0.w;
            acc[1][4]+=a.y*b1.x; acc[1][5]+=a.y*b1.y; acc[1][6]+=a.y*b1.z; acc[1][7]+=a.y*b1.w;
            acc[2][0]+=a.z*b0.x; acc[2][1]+=a.z*b0.y; acc[2][2]+=a.z*b0.z; acc[2][3]+=a.z*b0.w;
            acc[2][4]+=a.z*b1.x; acc[2][5]+=a.z*b1.y; acc[2][6]+=a.z*b1.z; acc[2][7]+=a.z*b1.w;
            acc[3][0]+=a.w*b0.x; acc[3][1]+=a.w*b0.y; acc[3][2]+=a.w*b0.z; acc[3][3]+=a.w*b0.w;
            acc[3][4]+=a.w*b1.x; acc[3][5]+=a.w*b1.y; acc[3][6]+=a.w*b1.z; acc[3][7]+=a.w*b1.w;
        }
    }

    #pragma unroll
    for (int i=0;i<4;i++){
        const int r = bm0 + tm + i;
        size_t base = ((size_t)(srel*2 + dir)*512 + (r & 511))*1024 + bn0 + tn;
        *(float4*)&p1out[base]   = *(float4*)&acc[i][0];
        *(float4*)&p1out[base+4] = *(float4*)&acc[i][4];
    }
}

// ===========================================================================
// Two-phase thrash-proof grid barrier.
// Phase 1: release (wb) + RELAXED arrive/poll (agent-scope atomics access the
//   coherence point WITHOUT invalidating L2 — unlike acquire polls).
// Single acquire (one L2 inv per block per step) strictly between phases.
// Phase 2: relaxed arrive/poll so no block starts reading until every block
//   finished invalidating -> L2 can dedupe the A-broadcast within each XCD.
// ===========================================================================
__device__ __forceinline__ void grid_bar2(unsigned* cnt, unsigned t)
{
    __syncthreads();
    if (threadIdx.x == 0) {
        __threadfence();   // release: write back dirty h/c lines toward L3
        __hip_atomic_fetch_add(cnt, 1u, __ATOMIC_RELAXED, __HIP_MEMORY_SCOPE_AGENT);
        const unsigned tgt1 = (2u*t + 1u) * 256u;
        while (__hip_atomic_load(cnt, __ATOMIC_RELAXED, __HIP_MEMORY_SCOPE_AGENT) < tgt1)
            __builtin_amdgcn_s_sleep(2);
        __threadfence();   // acquire: the ONE L2 invalidate for this step
        __hip_atomic_fetch_add(cnt, 1u, __ATOMIC_RELAXED, __HIP_MEMORY_SCOPE_AGENT);
        const unsigned tgt2 = (2u*t + 2u) * 256u;
        while (__hip_atomic_load(cnt, __ATOMIC_RELAXED, __HIP_MEMORY_SCOPE_AGENT) < tgt2)
            __builtin_amdgcn_s_sleep(2);
    }
    __syncthreads();
}

__device__ __forceinline__ void fma4(float* ac, float s, float4 v)
{
    ac[0] += s*v.x; ac[1] += s*v.y; ac[2] += s*v.z; ac[3] += s*v.w;
}

// ===========================================================================
// Prep: transpose final encoder state into [unit][row] layout + pW -> pwt.
// ===========================================================================
__global__ void prep_kernel(const float* __restrict__ h0, const float* __restrict__ c0,
                            const float* __restrict__ pW, float* __restrict__ hT0,
                            float* __restrict__ cT1, float* __restrict__ pwt)
{
    const int i = blockIdx.x*blockDim.x + threadIdx.x;
    if (i < 524288) {
        const int u = i >> 9, r = i & 511;
        hT0[i] = h0[(size_t)r*1024 + u];
        cT1[i] = c0[(size_t)r*1024 + u];
    }
    if (i < 131072) {
        const int k = i >> 7, v = i & 127;
        pwt[i] = pW[(size_t)v*1024 + k];
    }
}

// ===========================================================================
// Persistent decoder v3 (round-8 validated) + thrash-proof barrier.
// W-in-LDS (69.6 KB), transposed double-buffered state, double-buffered As,
// 1 grid barrier/step, k-split proj on transposed pwt.
// ===========================================================================
__global__ __launch_bounds__(1024)
void dec_persist(const float* __restrict__ Wih, const float* __restrict__ Whh,
                 const float* __restrict__ bias, const int* __restrict__ tok,
                 const float* __restrict__ emb, const float* __restrict__ pwt,
                 const float* __restrict__ pb, float* __restrict__ hT0,
                 float* __restrict__ hT1, float* __restrict__ cT0,
                 float* __restrict__ cT1, unsigned* __restrict__ bar,
                 float* __restrict__ dout)
{
    extern __shared__ float smem[];
    float* Ws = smem;                    // [1088][16]          69632 B
    float* As = smem + 17408;            // 2 x [16][512]       65536 B
    float* cs0  = As;                    // proj scratch aliases (seq. safe)
    float* cs1  = As + 1024;
    float* part = As + 2048;
    float* ls   = As + 4096;

    const int b = blockIdx.x, tid = threadIdx.x;
    const int bn0 = b*16;

    // ---- one-time W preload into LDS (gate-interleaved gather) ----
    {
        const int col = tid >> 6;
        const int n_g = bn0 + col;
        const int wrow = (n_g & 3)*1024 + (n_g >> 2);
        for (int k0 = (tid & 63)*4; k0 < 1088; k0 += 256) {
            float4 v;
            if (k0 < 64) v = *(const float4*)&Wih[(size_t)wrow*64 + k0];
            else         v = *(const float4*)&Whh[(size_t)wrow*1024 + (k0-64)];
            Ws[(k0+0)*16 + col] = v.x;
            Ws[(k0+1)*16 + col] = v.y;
            Ws[(k0+2)*16 + col] = v.z;
            Ws[(k0+3)*16 + col] = v.w;
        }
    }
    __syncthreads();

    const int m   = tid & 511;
    const int tn  = (tid >> 9) << 3;
    const int jh  = (bn0 + tn) >> 2;
    const float bi0 = bias[jh],   bf0 = bias[1024+jh],   bg0 = bias[2048+jh],   bo0 = bias[3072+jh];
    const float bi1 = bias[jh+1], bf1 = bias[1024+jh+1], bg1 = bias[2048+jh+1], bo1 = bias[3072+jh+1];
    const int sj  = tid >> 6;
    const int sr  = (tid & 63)*8;
    const int esm = tid >> 1, esq = tid & 1;

    for (int t = 0; t < T_DEC; ++t) {
        const float* hT_in  = (t & 1) ? hT1 : hT0;
        float*       hT_out = (t & 1) ? hT0 : hT1;
        const float* cT_in  = (t & 1) ? cT0 : cT1;
        float*       cT_out = (t & 1) ? cT1 : cT0;

        const int etok = tok[esm*S_OUT + t];

        float4 pre0 = *(const float4*)&emb[(size_t)etok*64 + esq*8];
        float4 pre1 = *(const float4*)&emb[(size_t)etok*64 + esq*8 + 4];
        float acc[8] = {};

        for (int kt = 0; kt < 68; ++kt) {
            float* buf = As + (kt & 1)*8192;
            if (kt < 4) {
                const int j0 = esq*8;
                buf[(j0+0)*512+esm]=pre0.x; buf[(j0+1)*512+esm]=pre0.y;
                buf[(j0+2)*512+esm]=pre0.z; buf[(j0+3)*512+esm]=pre0.w;
                buf[(j0+4)*512+esm]=pre1.x; buf[(j0+5)*512+esm]=pre1.y;
                buf[(j0+6)*512+esm]=pre1.z; buf[(j0+7)*512+esm]=pre1.w;
            } else {
                *(float4*)&buf[sj*512 + sr]     = pre0;
                *(float4*)&buf[sj*512 + sr + 4] = pre1;
            }
            if (kt+1 < 68) {
                if (kt+1 < 4) {
                    pre0 = *(const float4*)&emb[(size_t)etok*64 + (kt+1)*16 + esq*8];
                    pre1 = *(const float4*)&emb[(size_t)etok*64 + (kt+1)*16 + esq*8 + 4];
                } else {
                    const float* src = &hT_in[(size_t)((kt+1)*16 - 64 + sj)*512 + sr];
                    pre0 = *(const float4*)&src[0];
                    pre1 = *(const float4*)&src[4];
                }
            }
            __syncthreads();
            const int kg = kt*16;
            #pragma unroll
            for (int kk=0;kk<16;kk++){
                const float4 w0 = *(const float4*)&Ws[(kg+kk)*16 + tn];
                const float4 w1 = *(const float4*)&Ws[(kg+kk)*16 + tn + 4];
                const float a  = buf[kk*512 + m];
                fma4(acc+0, a, w0);
                fma4(acc+4, a, w1);
            }
        }

        // ---- LSTM epilogue: transposed state, fully-coalesced writes ----
        {
            float xi=acc[0]+bi0, xf=acc[1]+bf0, xg=acc[2]+bg0, xo=acc[3]+bo0;
            float ig=1.f/(1.f+expf(-xi)), fg=1.f/(1.f+expf(-xf));
            float gg=tanhf(xg), og=1.f/(1.f+expf(-xo));
            const size_t ci = (size_t)jh*512 + m;
            const float cn = fg*cT_in[ci] + ig*gg, hn = og*tanhf(cn);
            cT_out[ci] = cn; hT_out[ci] = hn;
        }
        {
            float xi=acc[4]+bi1, xf=acc[5]+bf1, xg=acc[6]+bg1, xo=acc[7]+bo1;
            float ig=1.f/(1.f+expf(-xi)), fg=1.f/(1.f+expf(-xf));
            float gg=tanhf(xg), og=1.f/(1.f+expf(-xo));
            const size_t ci = (size_t)(jh+1)*512 + m;
            const float cn = fg*cT_in[ci] + ig*gg, hn = og*tanhf(cn);
            cT_out[ci] = cn; hT_out[ci] = hn;
        }

        grid_bar2(bar, (unsigned)t);

        // ---- fused projection, rows 2b/2b+1, k-split across 16 waves ----
        {
            const float2 v = *(const float2*)&cT_out[(size_t)tid*512 + 2*b];
            cs0[tid] = v.x; cs1[tid] = v.y;
        }
        __syncthreads();
        {
            const int kgp = tid >> 7, pc = tid & 127;
            float a0 = 0.f, a1 = 0.f;
            const int k0 = kgp*128;
            #pragma unroll 4
            for (int ki=0; ki<128; ++ki){
                const float w = pwt[(size_t)(k0+ki)*128 + pc];
                a0 += w*cs0[k0+ki];
                a1 += w*cs1[k0+ki];
            }
            part[(kgp*2+0)*128 + pc] = a0;
            part[(kgp*2+1)*128 + pc] = a1;
        }
        __syncthreads();
        if (tid < 256) {
            const int pr = tid >> 7, pc = tid & 127;
            float s = pb[pc];
            #pragma unroll
            for (int kg2=0; kg2<8; ++kg2) s += part[(kg2*2+pr)*128 + pc];
            ls[pr*128 + pc] = s;
        }
        __syncthreads();
        if (tid < 128) {
            const int r = tid >> 6, lane = tid & 63;
            const int gb = 2*b + r;
            const float v0 = ls[r*128 + lane], v1 = ls[r*128 + lane + 64];
            float mv; int mi;
            if (v1 > v0){ mv=v1; mi=lane+64; } else { mv=v0; mi=lane; }
            #pragma unroll
            for (int o=32;o>=1;o>>=1){
                const float ov = __shfl_xor(mv, o);
                const int   oi = __shfl_xor(mi, o);
                if (ov > mv || (ov == mv && oi < mi)){ mv=ov; mi=oi; }
            }
            float e = expf(v0-mv) + expf(v1-mv);
            #pragma unroll
            for (int o=32;o>=1;o>>=1) e += __shfl_xor(e, o);
            if (lane == 0){
                const int tnx = tok[gb*S_OUT + t + 1];
                const float logp = ls[r*128 + tnx] - mv - logf(e);
                const float cn = ((t==0)?0.f:dout[T_DEC*B + gb]) + logp;
                dout[T_DEC*B + gb] = cn;
                dout[t*B + gb] = (float)mi;
            }
        }
        __syncthreads();   // protect As region (proj scratch) before next staging
    }
}

__global__ void zero_kernel(float* __restrict__ p, int n4){
    int i = blockIdx.x*blockDim.x + threadIdx.x;
    if (i < n4) *(float4*)&p[i*4] = float4{0.f,0.f,0.f,0.f};
}

extern "C" void kernel_launch(void* const* d_in, const int* in_sizes, int n_in,
                              void* d_out, int out_size, void* d_ws, size_t ws_size,
                              hipStream_t stream)
{
    const int*   input_tokens  = (const int*)d_in[0];
    const int*   output_tokens = (const int*)d_in[1];
    const float* in_emb  = (const float*)d_in[2];
    const float* eWih0   = (const float*)d_in[3];
    const float* eWhh0   = (const float*)d_in[4];
    const float* eb0     = (const float*)d_in[5];
    const float* eWih1   = (const float*)d_in[6];
    const float* eWhh1   = (const float*)d_in[7];
    const float* eb1     = (const float*)d_in[8];
    const float* out_emb = (const float*)d_in[9];
    const float* dWih    = (const float*)d_in[10];
    const float* dWhh    = (const float*)d_in[11];
    const float* db      = (const float*)d_in[12];
    const float* pW      = (const float*)d_in[13];
    const float* pb      = (const float*)d_in[14];

    size_t ws_fl = ws_size / 4;
    if (ws_fl < (size_t)O_P1) return;

    int CH = 0;
    if      (ws_fl >= (size_t)O_P1 + 16u*1048576u) CH = 16;
    else if (ws_fl >= (size_t)O_P1 +  8u*1048576u) CH = 8;
    else if (ws_fl >= (size_t)O_P1 +  4u*1048576u) CH = 4;
    else if (ws_fl >= (size_t)O_P1 +  2u*1048576u) CH = 2;

    float* ws   = (float*)d_ws;
    float* dout = (float*)d_out;

    float* h[2]   = { ws + O_H0, ws + O_H1 };
    float* c      = ws + O_C;
    unsigned* bar = (unsigned*)(ws + O_BAR);
    float* hs0    = ws + O_HS0;
    float* p1     = ws + O_P1;
    float* hT0    = ws + D_HT0;
    float* hT1    = ws + D_HT1;
    float* cT0    = ws + D_CT0;
    float* cT1    = ws + D_CT1;
    float* pwt    = ws + D_PWT;

    // zero h0,h1,c,bar
    zero_kernel<<<(O_HS0/4 + 255)/256, 256, 0, stream>>>(ws, O_HS0/4);

    // ---- encoder layer 0 (round-2 validated path) ----
    for (int t=0;t<S_IN;t++)
        enc_step<0><<<dim3(8,16,2),256,0,stream>>>(eWih0, eWhh0, eb0,
            input_tokens, in_emb, nullptr, h[t&1], h[(t+1)&1], c, hs0, nullptr, t);

    // ---- encoder layer 1 (round-2 validated path) ----
    if (CH) {
        for (int s0=0; s0<S_IN; s0+=CH) {
            gemm_p1<<<dim3(CH*8,16,2),128,0,stream>>>(eWih1, hs0, p1, s0);
            for (int s=s0; s<s0+CH; ++s)
                enc_step<1><<<dim3(8,16,2),256,0,stream>>>(eWih1, eWhh1, eb1,
                    nullptr, nullptr, nullptr, h[s&1], h[(s+1)&1], c, nullptr,
                    p1 + (size_t)(s-s0)*2*512*1024, s);
        }
    } else {
        for (int t=0;t<S_IN;t++)
            enc_step<2><<<dim3(8,16,2),256,0,stream>>>(eWih1, eWhh1, eb1,
                nullptr, nullptr, hs0, h[t&1], h[(t+1)&1], c, nullptr, nullptr, t);
    }

    // ---- prep: transpose state + pW (hs0 is dead from here on) ----
    prep_kernel<<<2048,256,0,stream>>>(h[0], c, pW, hT0, cT1, pwt);

    // ---- persistent decoder v3 + thrash-proof barrier ----
    dec_persist<<<256, 1024, 135168, stream>>>(dWih, dWhh, db, output_tokens,
                                               out_emb, pwt, pb, hT0, hT1,
                                               cT0, cT1, bar, dout);
}